// Round 12
// baseline (141.313 us; speedup 1.0000x reference)
//
#include <hip/hip_runtime.h>

// YoloLoss — R12: R11 body (no-LDS, 1 thread = 1 cell) + fused last-block
// reduction (kills the second kernel launch tail).
//  * per-block partial via agent-scope atomic store; counter fetch_add
//    (acq_rel, agent); last block reduces all partials via agent-scope
//    atomic loads (coherent point -> no cross-XCD false-sharing hazard).
//  * deterministic: fixed summation order, last-block identity irrelevant.
//  * counter zeroed per launch via 4-byte hipMemsetAsync (graph-legal).
// Inputs: pred f32[NC,30], tbox f32[NC,4], tcls f32[NC,20], objmap i32[NC].
// Output: d_out[0] = scalar loss (f32).

constexpr int TPB = 256;
constexpr float EPSV = 1e-10f;

__device__ __forceinline__ float clamp01(float v) {
    return fminf(fmaxf(v, 0.0f), 1.0f);
}

template <bool FUSED>
__global__ __launch_bounds__(TPB, 4) void yolo_part(
    const float* __restrict__ pred,
    const float* __restrict__ tbox,
    const float* __restrict__ tcls,
    const int* __restrict__ objmap,
    float* __restrict__ partial,     // FUSED: nblk floats in d_ws
    int* __restrict__ counter,       // FUSED: 1 int in d_ws (zeroed/launch)
    float* __restrict__ out,
    int nblk, float inv_n)
{
    __shared__ float wsum[4];
    __shared__ int lds_done;

    const int t = threadIdx.x;
    const size_t cell = (size_t)blockIdx.x * TPB + t;

    // ---- coalesced per-cell loads ----
    const float4 tb = reinterpret_cast<const float4*>(tbox)[cell];
    const int ob = objmap[cell];

    // ---- whole cell record: 15 x float2 (8B-aligned, stride 120 B) ----
    const float2* pp = reinterpret_cast<const float2*>(pred) + cell * 15;
    float2 P0 = pp[0], P1 = pp[1], P2 = pp[2], P3 = pp[3], P4 = pp[4];
    float2 P5 = pp[5], P6 = pp[6], P7 = pp[7], P8 = pp[8], P9 = pp[9];
    float2 P10 = pp[10], P11 = pp[11], P12 = pp[12], P13 = pp[13],
           P14 = pp[14];

    // ---- own-cell class targets: 5 x float4 (stride 80 B) ----
    const float4* tc = reinterpret_cast<const float4*>(tcls) + cell * 5;
    const float4 T0 = tc[0], T1 = tc[1], T2 = tc[2], T3 = tc[3], T4 = tc[4];

    const float objf = ob ? 1.0f : 0.0f;
    const float tx = tb.x, ty = tb.y, tw = tb.z, th = tb.w;

    // ---- box terms ----
    const float invS = 1.0f / 14.0f;
    const float tcx = tx * invS, tcy = ty * invS;
    const float tww = fmaxf(tw, EPSV), thh = fmaxf(th, EPSV);
    const float tx1 = clamp01(tcx - 0.5f * tww);
    const float ty1 = clamp01(tcy - 0.5f * thh);
    const float tx2 = clamp01(tcx + 0.5f * tww);
    const float ty2 = clamp01(tcy + 0.5f * thh);
    const float tarea = (tx2 - tx1) * (ty2 - ty1);

    const float p0x = P0.x, p0y = P0.y, p0w = P1.x, p0h = P1.y, c0 = P2.x;
    const float p1x = P2.y, p1y = P3.x, p1w = P3.y, p1h = P4.x, c1 = P4.y;

    float iou0, iou1;
    {
        const float cx = p0x * invS, cy = p0y * invS;
        const float ww = fmaxf(p0w, EPSV), hh = fmaxf(p0h, EPSV);
        const float x1 = clamp01(cx - 0.5f * ww), y1 = clamp01(cy - 0.5f * hh);
        const float x2 = clamp01(cx + 0.5f * ww), y2 = clamp01(cy + 0.5f * hh);
        const float lx = fmaxf(x1, tx1), ly = fmaxf(y1, ty1);
        const float rx = fminf(x2, tx2), ry = fminf(y2, ty2);
        const float inter = fmaxf(rx - lx, 0.0f) * fmaxf(ry - ly, 0.0f);
        const float pa = (x2 - x1) * (y2 - y1);
        iou0 = inter / (pa + tarea - inter + EPSV);
    }
    {
        const float cx = p1x * invS, cy = p1y * invS;
        const float ww = fmaxf(p1w, EPSV), hh = fmaxf(p1h, EPSV);
        const float x1 = clamp01(cx - 0.5f * ww), y1 = clamp01(cy - 0.5f * hh);
        const float x2 = clamp01(cx + 0.5f * ww), y2 = clamp01(cy + 0.5f * hh);
        const float lx = fmaxf(x1, tx1), ly = fmaxf(y1, ty1);
        const float rx = fminf(x2, tx2), ry = fminf(y2, ty2);
        const float inter = fmaxf(rx - lx, 0.0f) * fmaxf(ry - ly, 0.0f);
        const float pa = (x2 - x1) * (y2 - y1);
        iou1 = inter / (pa + tarea - inter + EPSV);
    }

    const float d0 = c0 - 0.05f, d1 = c1 - 0.05f;
    const float noobj = (d0 * d0 + d1 * d1) * (1.0f - objf);

    const bool sel = iou1 > iou0;                    // tie -> box 0
    const float biou = fminf((sel ? iou1 : iou0) + 0.5f, 0.95f);
    const float bx = sel ? p1x : p0x;
    const float by = sel ? p1y : p0y;
    const float bw = sel ? p1w : p0w;
    const float bh = sel ? p1h : p0h;
    const float bc = sel ? c1 : c0;

    const float spw = sqrtf(fabsf(bw) + 1e-6f);
    const float stw = sqrtf(fabsf(tw) + 1e-6f);
    const float sph = sqrtf(fabsf(bh) + 1e-6f);
    const float sth = sqrtf(fabsf(th) + 1e-6f);
    const float dx = bx - tx, dy = by - ty, dw = spw - stw, dh = sph - sth;
    const float reg = dx * dx + dy * dy + dw * dw + dh * dh;
    const float dcf = bc - biou;

    float acc = noobj * 0.5f + (reg * 10.0f + dcf * dcf * 10.0f) * objf;

    // ---- class BCE, own cell: -ln2*(lq + t*(lp-lq)) ----
    float csum = 0.0f;
    {
        const float2 pa2[10] = {P5, P6, P7, P8, P9, P10, P11, P12, P13, P14};
        const float4 tt[5] = {T0, T1, T2, T3, T4};
        #pragma unroll
        for (int k = 0; k < 5; ++k) {
            const float pv[4] = {pa2[2 * k].x, pa2[2 * k].y,
                                 pa2[2 * k + 1].x, pa2[2 * k + 1].y};
            const float tvf[4] = {tt[k].x, tt[k].y, tt[k].z, tt[k].w};
            #pragma unroll
            for (int u = 0; u < 4; ++u) {
                const float p = fminf(fmaxf(pv[u], 1e-7f), 1.0f - 1e-7f);
                const float lp = __log2f(p);
                const float lq = __log2f(1.0f - p);
                csum += lq + tvf[u] * (lp - lq);
            }
        }
    }
    acc += csum * objf * (-0.5f * 0.69314718055994530942f);

    // ---- block reduce: wave shfl -> LDS ----
    #pragma unroll
    for (int off = 32; off > 0; off >>= 1) acc += __shfl_down(acc, off);
    if ((t & 63) == 0) wsum[t >> 6] = acc;
    __syncthreads();

    if (!FUSED) {
        if (t == 0) atomicAdd(out, (wsum[0] + wsum[1] + wsum[2] + wsum[3]) * inv_n);
        return;
    }

    // ---- publish partial + last-block-done ----
    if (t == 0) {
        const float blocksum = wsum[0] + wsum[1] + wsum[2] + wsum[3];
        __hip_atomic_store(&partial[blockIdx.x], blocksum,
                           __ATOMIC_RELAXED, __HIP_MEMORY_SCOPE_AGENT);
        const int old = __hip_atomic_fetch_add(counter, 1, __ATOMIC_ACQ_REL,
                                               __HIP_MEMORY_SCOPE_AGENT);
        lds_done = (old == nblk - 1) ? 1 : 0;
    }
    __syncthreads();

    if (lds_done) {
        float s = 0.0f;
        for (int i = t; i < nblk; i += TPB)
            s += __hip_atomic_load(&partial[i], __ATOMIC_RELAXED,
                                   __HIP_MEMORY_SCOPE_AGENT);
        #pragma unroll
        for (int off = 32; off > 0; off >>= 1) s += __shfl_down(s, off);
        if ((t & 63) == 0) wsum[t >> 6] = s;
        __syncthreads();
        if (t == 0) out[0] = (wsum[0] + wsum[1] + wsum[2] + wsum[3]) * inv_n;
    }
}

extern "C" void kernel_launch(void* const* d_in, const int* in_sizes, int n_in,
                              void* d_out, int out_size, void* d_ws, size_t ws_size,
                              hipStream_t stream) {
    const float* pred = (const float*)d_in[0];
    const float* tbox = (const float*)d_in[1];
    const float* tcls = (const float*)d_in[2];
    const int* objmap = (const int*)d_in[3];
    float* out = (float*)d_out;

    const int ncells = in_sizes[3];          // N * S * S (802816)
    const int n_imgs = ncells / 196;         // N (4096)
    const float inv_n = 1.0f / (float)n_imgs;
    const int nblk = ncells / TPB;           // 3136

    const size_t need = (size_t)nblk * sizeof(float) + sizeof(int);
    if (ws_size >= need) {
        float* partial = (float*)d_ws;
        int* counter = (int*)((char*)d_ws + (size_t)nblk * sizeof(float));
        hipMemsetAsync(counter, 0, sizeof(int), stream);   // reset per launch
        yolo_part<true><<<nblk, TPB, 0, stream>>>(pred, tbox, tcls, objmap,
                                                  partial, counter, out,
                                                  nblk, inv_n);
    } else {
        hipMemsetAsync(out, 0, sizeof(float), stream);
        yolo_part<false><<<nblk, TPB, 0, stream>>>(pred, tbox, tcls, objmap,
                                                   nullptr, nullptr, out,
                                                   nblk, inv_n);
    }
}

// Round 13
// 58.899 us; speedup vs baseline: 2.3993x; 2.3993x over previous
//
#include <hip/hip_runtime.h>

// YoloLoss — R13: R11 body (no-LDS, 1 thread = 1 cell, the 34.6 µs best)
// with the two-kernel tail replaced by one RELAXED device-scope atomicAdd
// per block (no acquire/release fences — R12's ACQ_REL agent fetch_add per
// block invalidated caches 3136x and collapsed BW to 0.4 TB/s).
// Inputs: pred f32[NC,30], tbox f32[NC,4], tcls f32[NC,20], objmap i32[NC].
// Output: d_out[0] = scalar loss (f32).

constexpr int TPB = 256;
constexpr float EPSV = 1e-10f;

__device__ __forceinline__ float clamp01(float v) {
    return fminf(fmaxf(v, 0.0f), 1.0f);
}

__global__ __launch_bounds__(TPB, 4) void yolo_part(
    const float* __restrict__ pred,
    const float* __restrict__ tbox,
    const float* __restrict__ tcls,
    const int* __restrict__ objmap,
    float* __restrict__ out,
    float inv_n)
{
    __shared__ float wsum[4];

    const int t = threadIdx.x;
    const size_t cell = (size_t)blockIdx.x * TPB + t;

    // ---- coalesced per-cell loads ----
    const float4 tb = reinterpret_cast<const float4*>(tbox)[cell];
    const int ob = objmap[cell];

    // ---- whole cell record: 15 x float2 (8B-aligned, stride 120 B) ----
    const float2* pp = reinterpret_cast<const float2*>(pred) + cell * 15;
    float2 P0 = pp[0], P1 = pp[1], P2 = pp[2], P3 = pp[3], P4 = pp[4];
    float2 P5 = pp[5], P6 = pp[6], P7 = pp[7], P8 = pp[8], P9 = pp[9];
    float2 P10 = pp[10], P11 = pp[11], P12 = pp[12], P13 = pp[13],
           P14 = pp[14];

    // ---- own-cell class targets: 5 x float4 (stride 80 B) ----
    const float4* tc = reinterpret_cast<const float4*>(tcls) + cell * 5;
    const float4 T0 = tc[0], T1 = tc[1], T2 = tc[2], T3 = tc[3], T4 = tc[4];

    const float objf = ob ? 1.0f : 0.0f;
    const float tx = tb.x, ty = tb.y, tw = tb.z, th = tb.w;

    // ---- box terms ----
    const float invS = 1.0f / 14.0f;
    const float tcx = tx * invS, tcy = ty * invS;
    const float tww = fmaxf(tw, EPSV), thh = fmaxf(th, EPSV);
    const float tx1 = clamp01(tcx - 0.5f * tww);
    const float ty1 = clamp01(tcy - 0.5f * thh);
    const float tx2 = clamp01(tcx + 0.5f * tww);
    const float ty2 = clamp01(tcy + 0.5f * thh);
    const float tarea = (tx2 - tx1) * (ty2 - ty1);

    const float p0x = P0.x, p0y = P0.y, p0w = P1.x, p0h = P1.y, c0 = P2.x;
    const float p1x = P2.y, p1y = P3.x, p1w = P3.y, p1h = P4.x, c1 = P4.y;

    float iou0, iou1;
    {
        const float cx = p0x * invS, cy = p0y * invS;
        const float ww = fmaxf(p0w, EPSV), hh = fmaxf(p0h, EPSV);
        const float x1 = clamp01(cx - 0.5f * ww), y1 = clamp01(cy - 0.5f * hh);
        const float x2 = clamp01(cx + 0.5f * ww), y2 = clamp01(cy + 0.5f * hh);
        const float lx = fmaxf(x1, tx1), ly = fmaxf(y1, ty1);
        const float rx = fminf(x2, tx2), ry = fminf(y2, ty2);
        const float inter = fmaxf(rx - lx, 0.0f) * fmaxf(ry - ly, 0.0f);
        const float pa = (x2 - x1) * (y2 - y1);
        iou0 = inter / (pa + tarea - inter + EPSV);
    }
    {
        const float cx = p1x * invS, cy = p1y * invS;
        const float ww = fmaxf(p1w, EPSV), hh = fmaxf(p1h, EPSV);
        const float x1 = clamp01(cx - 0.5f * ww), y1 = clamp01(cy - 0.5f * hh);
        const float x2 = clamp01(cx + 0.5f * ww), y2 = clamp01(cy + 0.5f * hh);
        const float lx = fmaxf(x1, tx1), ly = fmaxf(y1, ty1);
        const float rx = fminf(x2, tx2), ry = fminf(y2, ty2);
        const float inter = fmaxf(rx - lx, 0.0f) * fmaxf(ry - ly, 0.0f);
        const float pa = (x2 - x1) * (y2 - y1);
        iou1 = inter / (pa + tarea - inter + EPSV);
    }

    const float d0 = c0 - 0.05f, d1 = c1 - 0.05f;
    const float noobj = (d0 * d0 + d1 * d1) * (1.0f - objf);

    const bool sel = iou1 > iou0;                    // tie -> box 0
    const float biou = fminf((sel ? iou1 : iou0) + 0.5f, 0.95f);
    const float bx = sel ? p1x : p0x;
    const float by = sel ? p1y : p0y;
    const float bw = sel ? p1w : p0w;
    const float bh = sel ? p1h : p0h;
    const float bc = sel ? c1 : c0;

    const float spw = sqrtf(fabsf(bw) + 1e-6f);
    const float stw = sqrtf(fabsf(tw) + 1e-6f);
    const float sph = sqrtf(fabsf(bh) + 1e-6f);
    const float sth = sqrtf(fabsf(th) + 1e-6f);
    const float dx = bx - tx, dy = by - ty, dw = spw - stw, dh = sph - sth;
    const float reg = dx * dx + dy * dy + dw * dw + dh * dh;
    const float dcf = bc - biou;

    float acc = noobj * 0.5f + (reg * 10.0f + dcf * dcf * 10.0f) * objf;

    // ---- class BCE, own cell: -ln2*(lq + t*(lp-lq)) ----
    float csum = 0.0f;
    {
        const float2 pa2[10] = {P5, P6, P7, P8, P9, P10, P11, P12, P13, P14};
        const float4 tt[5] = {T0, T1, T2, T3, T4};
        #pragma unroll
        for (int k = 0; k < 5; ++k) {
            const float pv[4] = {pa2[2 * k].x, pa2[2 * k].y,
                                 pa2[2 * k + 1].x, pa2[2 * k + 1].y};
            const float tvf[4] = {tt[k].x, tt[k].y, tt[k].z, tt[k].w};
            #pragma unroll
            for (int u = 0; u < 4; ++u) {
                const float p = fminf(fmaxf(pv[u], 1e-7f), 1.0f - 1e-7f);
                const float lp = __log2f(p);
                const float lq = __log2f(1.0f - p);
                csum += lq + tvf[u] * (lp - lq);
            }
        }
    }
    acc += csum * objf * (-0.5f * 0.69314718055994530942f);

    // ---- block reduce -> one relaxed device-scope atomicAdd ----
    #pragma unroll
    for (int off = 32; off > 0; off >>= 1) acc += __shfl_down(acc, off);
    if ((t & 63) == 0) wsum[t >> 6] = acc;
    __syncthreads();
    if (t == 0)
        atomicAdd(out, (wsum[0] + wsum[1] + wsum[2] + wsum[3]) * inv_n);
}

extern "C" void kernel_launch(void* const* d_in, const int* in_sizes, int n_in,
                              void* d_out, int out_size, void* d_ws, size_t ws_size,
                              hipStream_t stream) {
    const float* pred = (const float*)d_in[0];
    const float* tbox = (const float*)d_in[1];
    const float* tcls = (const float*)d_in[2];
    const int* objmap = (const int*)d_in[3];
    float* out = (float*)d_out;

    const int ncells = in_sizes[3];          // N * S * S (802816)
    const int n_imgs = ncells / 196;         // N (4096)
    const float inv_n = 1.0f / (float)n_imgs;
    const int nblk = ncells / TPB;           // 3136

    hipMemsetAsync(out, 0, sizeof(float), stream);   // graph-legal
    yolo_part<<<nblk, TPB, 0, stream>>>(pred, tbox, tcls, objmap, out, inv_n);
}

// Round 14
// 34.592 us; speedup vs baseline: 4.0851x; 1.7027x over previous
//
#include <hip/hip_runtime.h>

// YoloLoss — FINAL (revert to R11, the measured best: 34.6 µs wall).
// Structure: no-LDS, 1 thread = 1 whole cell.
//  * pred record (30 f32 = 120 B) read directly as 15x float2 (stride 120 B,
//    8B-aligned). Per-instruction the wave spans ~60 cache lines, but all 15
//    instructions touch the SAME lines -> L1 serves re-touches, HBM traffic
//    unchanged (FETCH ~87 MB). tcls as 5x float4 (stride 80 B), tbox/obj
//    coalesced.
//  * zero LDS, zero barriers, zero DMA: compiler freely interleaves all 22
//    loads with compute and keeps them outstanding across the body.
//  * per-WAVE partial -> d_ws (plain stores; atomics on d_out are slow
//    [R13: +24 µs] and per-block acq_rel fences collapse BW [R12]);
//    tiny second kernel reduces 12544 partials and plain-stores out[0].
// Inputs: pred f32[NC,30], tbox f32[NC,4], tcls f32[NC,20], objmap i32[NC].
// Output: d_out[0] = scalar loss (f32).

constexpr int TPB = 256;
constexpr float EPSV = 1e-10f;

__device__ __forceinline__ float clamp01(float v) {
    return fminf(fmaxf(v, 0.0f), 1.0f);
}

template <bool ATOMIC>
__global__ __launch_bounds__(TPB, 4) void yolo_part(
    const float* __restrict__ pred,
    const float* __restrict__ tbox,
    const float* __restrict__ tcls,
    const int* __restrict__ objmap,
    float* __restrict__ partial,
    float* __restrict__ out,
    float inv_n)
{
    const int t = threadIdx.x;
    const size_t cell = (size_t)blockIdx.x * TPB + t;

    // ---- coalesced per-cell loads ----
    const float4 tb = reinterpret_cast<const float4*>(tbox)[cell];
    const int ob = objmap[cell];

    // ---- whole cell record: 15 x float2 (8B-aligned, stride 120 B) ----
    const float2* pp = reinterpret_cast<const float2*>(pred) + cell * 15;
    float2 P0 = pp[0], P1 = pp[1], P2 = pp[2], P3 = pp[3], P4 = pp[4];
    float2 P5 = pp[5], P6 = pp[6], P7 = pp[7], P8 = pp[8], P9 = pp[9];
    float2 P10 = pp[10], P11 = pp[11], P12 = pp[12], P13 = pp[13],
           P14 = pp[14];

    // ---- own-cell class targets: 5 x float4 (16B-aligned, stride 80 B) ----
    const float4* tc = reinterpret_cast<const float4*>(tcls) + cell * 5;
    const float4 T0 = tc[0], T1 = tc[1], T2 = tc[2], T3 = tc[3], T4 = tc[4];

    const float objf = ob ? 1.0f : 0.0f;
    const float tx = tb.x, ty = tb.y, tw = tb.z, th = tb.w;

    // ---- box terms ----
    const float invS = 1.0f / 14.0f;
    const float tcx = tx * invS, tcy = ty * invS;
    const float tww = fmaxf(tw, EPSV), thh = fmaxf(th, EPSV);
    const float tx1 = clamp01(tcx - 0.5f * tww);
    const float ty1 = clamp01(tcy - 0.5f * thh);
    const float tx2 = clamp01(tcx + 0.5f * tww);
    const float ty2 = clamp01(tcy + 0.5f * thh);
    const float tarea = (tx2 - tx1) * (ty2 - ty1);

    const float p0x = P0.x, p0y = P0.y, p0w = P1.x, p0h = P1.y, c0 = P2.x;
    const float p1x = P2.y, p1y = P3.x, p1w = P3.y, p1h = P4.x, c1 = P4.y;

    float iou0, iou1;
    {
        const float cx = p0x * invS, cy = p0y * invS;
        const float ww = fmaxf(p0w, EPSV), hh = fmaxf(p0h, EPSV);
        const float x1 = clamp01(cx - 0.5f * ww), y1 = clamp01(cy - 0.5f * hh);
        const float x2 = clamp01(cx + 0.5f * ww), y2 = clamp01(cy + 0.5f * hh);
        const float lx = fmaxf(x1, tx1), ly = fmaxf(y1, ty1);
        const float rx = fminf(x2, tx2), ry = fminf(y2, ty2);
        const float inter = fmaxf(rx - lx, 0.0f) * fmaxf(ry - ly, 0.0f);
        const float pa = (x2 - x1) * (y2 - y1);
        iou0 = inter / (pa + tarea - inter + EPSV);
    }
    {
        const float cx = p1x * invS, cy = p1y * invS;
        const float ww = fmaxf(p1w, EPSV), hh = fmaxf(p1h, EPSV);
        const float x1 = clamp01(cx - 0.5f * ww), y1 = clamp01(cy - 0.5f * hh);
        const float x2 = clamp01(cx + 0.5f * ww), y2 = clamp01(cy + 0.5f * hh);
        const float lx = fmaxf(x1, tx1), ly = fmaxf(y1, ty1);
        const float rx = fminf(x2, tx2), ry = fminf(y2, ty2);
        const float inter = fmaxf(rx - lx, 0.0f) * fmaxf(ry - ly, 0.0f);
        const float pa = (x2 - x1) * (y2 - y1);
        iou1 = inter / (pa + tarea - inter + EPSV);
    }

    const float d0 = c0 - 0.05f, d1 = c1 - 0.05f;
    const float noobj = (d0 * d0 + d1 * d1) * (1.0f - objf);

    const bool sel = iou1 > iou0;                    // tie -> box 0
    const float biou = fminf((sel ? iou1 : iou0) + 0.5f, 0.95f);
    const float bx = sel ? p1x : p0x;
    const float by = sel ? p1y : p0y;
    const float bw = sel ? p1w : p0w;
    const float bh = sel ? p1h : p0h;
    const float bc = sel ? c1 : c0;

    const float spw = sqrtf(fabsf(bw) + 1e-6f);
    const float stw = sqrtf(fabsf(tw) + 1e-6f);
    const float sph = sqrtf(fabsf(bh) + 1e-6f);
    const float sth = sqrtf(fabsf(th) + 1e-6f);
    const float dx = bx - tx, dy = by - ty, dw = spw - stw, dh = sph - sth;
    const float reg = dx * dx + dy * dy + dw * dw + dh * dh;
    const float dcf = bc - biou;

    float acc = noobj * 0.5f + (reg * 10.0f + dcf * dcf * 10.0f) * objf;

    // ---- class BCE, own cell, all static indices:
    //      bce = -ln2*(lq + t*(lp-lq)), lp=log2(p), lq=log2(1-p) ----
    float csum = 0.0f;
    {
        const float2 pa2[10] = {P5, P6, P7, P8, P9, P10, P11, P12, P13, P14};
        const float4 tt[5] = {T0, T1, T2, T3, T4};
        #pragma unroll
        for (int k = 0; k < 5; ++k) {
            const float pv[4] = {pa2[2 * k].x, pa2[2 * k].y,
                                 pa2[2 * k + 1].x, pa2[2 * k + 1].y};
            const float tvf[4] = {tt[k].x, tt[k].y, tt[k].z, tt[k].w};
            #pragma unroll
            for (int u = 0; u < 4; ++u) {
                const float p = fminf(fmaxf(pv[u], 1e-7f), 1.0f - 1e-7f);
                const float lp = __log2f(p);
                const float lq = __log2f(1.0f - p);
                csum += lq + tvf[u] * (lp - lq);
            }
        }
    }
    acc += csum * objf * (-0.5f * 0.69314718055994530942f);

    // ---- wave reduce; per-WAVE partial store (no barrier, no LDS) ----
    #pragma unroll
    for (int off = 32; off > 0; off >>= 1) acc += __shfl_down(acc, off);
    if ((t & 63) == 0) {
        if (ATOMIC) atomicAdd(out, acc * inv_n);
        else partial[blockIdx.x * 4 + (t >> 6)] = acc;
    }
}

__global__ __launch_bounds__(1024) void yolo_reduce(
    const float* __restrict__ partial, float* __restrict__ out,
    int np4, float inv_n)
{
    __shared__ float ws[16];
    const int t = threadIdx.x;
    const float4* p4 = reinterpret_cast<const float4*>(partial);
    float s = 0.0f;
    for (int i = t; i < np4; i += 1024) {
        const float4 v = p4[i];
        s += (v.x + v.y) + (v.z + v.w);
    }
    #pragma unroll
    for (int off = 32; off > 0; off >>= 1) s += __shfl_down(s, off);
    if ((t & 63) == 0) ws[t >> 6] = s;
    __syncthreads();
    if (t < 16) {
        s = ws[t];
        #pragma unroll
        for (int off = 8; off > 0; off >>= 1) s += __shfl_down(s, off, 16);
        if (t == 0) out[0] = s * inv_n;
    }
}

extern "C" void kernel_launch(void* const* d_in, const int* in_sizes, int n_in,
                              void* d_out, int out_size, void* d_ws, size_t ws_size,
                              hipStream_t stream) {
    const float* pred = (const float*)d_in[0];
    const float* tbox = (const float*)d_in[1];
    const float* tcls = (const float*)d_in[2];
    const int* objmap = (const int*)d_in[3];
    float* out = (float*)d_out;

    const int ncells = in_sizes[3];          // N * S * S (802816)
    const int n_imgs = ncells / 196;         // N (4096)
    const float inv_n = 1.0f / (float)n_imgs;
    const int nblk = ncells / TPB;           // 3136
    const int npart = nblk * 4;              // 12544 wave partials

    if (ws_size >= (size_t)npart * sizeof(float)) {
        float* partial = (float*)d_ws;
        yolo_part<false><<<nblk, TPB, 0, stream>>>(pred, tbox, tcls, objmap,
                                                   partial, nullptr, inv_n);
        yolo_reduce<<<1, 1024, 0, stream>>>(partial, out, npart / 4, inv_n);
    } else {
        hipMemsetAsync(out, 0, sizeof(float), stream);
        yolo_part<true><<<nblk, TPB, 0, stream>>>(pred, tbox, tcls, objmap,
                                                  nullptr, out, inv_n);
    }
}